// Round 2
// baseline (151.960 us; speedup 1.0000x reference)
//
#include <hip/hip_runtime.h>
#include <hip/hip_bf16.h>
#include <math.h>

#define N_ROWS 8192
#define DIM 256
#define NCLS 128
// scale folded into normalized rows: sqrt((1/0.07) * log2(e))
#define ROW_SCALE 4.539816f
#define CLAMP_Y 14.426950408889634f   // 10 * log2(e)
#define NEG2C (-28.853900817779268f)  // -2 * CLAMP_Y
#define LN2F 0.6931471805599453f

typedef short bf16x8 __attribute__((ext_vector_type(8)));
typedef float f32x4 __attribute__((ext_vector_type(4)));

#define AS1 __attribute__((address_space(1)))
#define AS3 __attribute__((address_space(3)))

__device__ __forceinline__ void load16_to_lds(const void* g, void* lds) {
  // LDS dest = wave-uniform base + lane*16 (HW rule); gptr is per-lane
  __builtin_amdgcn_global_load_lds((const AS1 void*)g, (AS3 void*)lds, 16, 0, 0);
}

__device__ __forceinline__ unsigned short f2bf(float x) {
  union { __hip_bfloat16 b; unsigned short u; } cv;
  cv.b = __float2bfloat16(x);
  return cv.u;
}

__device__ __forceinline__ float fast_exp2(float x) {
#if __has_builtin(__builtin_amdgcn_exp2f)
  return __builtin_amdgcn_exp2f(x);
#else
  return exp2f(x);
#endif
}

// clamp(x, -2C, 0) in one v_med3_f32
__device__ __forceinline__ float clamp_neg(float x) {
#if __has_builtin(__builtin_amdgcn_fmed3f)
  return __builtin_amdgcn_fmed3f(x, NEG2C, 0.0f);
#else
  return fminf(0.0f, fmaxf(NEG2C, x));
#endif
}

// ---------------- row-normalize*ROW_SCALE -> bf16, zero S/P -----------------
__global__ __launch_bounds__(256) void normalize_kernel(const float* __restrict__ f,
                                                        unsigned short* __restrict__ fnb,
                                                        float* __restrict__ S,
                                                        float* __restrict__ P) {
  const int row = blockIdx.x * 4 + (threadIdx.x >> 6);
  const int l = threadIdx.x & 63;
  const float4 v = ((const float4*)(f + (size_t)row * DIM))[l];
  float ss = v.x * v.x + v.y * v.y + v.z * v.z + v.w * v.w;
#pragma unroll
  for (int m = 32; m >= 1; m >>= 1) ss += __shfl_xor(ss, m, 64);
  const float inv = ROW_SCALE / fmaxf(sqrtf(ss), 1e-6f);
  ushort4 o;
  o.x = f2bf(v.x * inv);
  o.y = f2bf(v.y * inv);
  o.z = f2bf(v.z * inv);
  o.w = f2bf(v.w * inv);
  ((ushort4*)(fnb + (size_t)row * DIM))[l] = o;
  if (l == 0) { S[row] = 0.f; P[row] = 0.f; }
}

// ---------------- triangular-strip GEMM + exp/positive reductions -----------
// 1056 blocks x 512 threads (8 waves): block = (bi, chunk of up to 2 j-tiles).
// A (128x256 bf16, 64 KB) resident in LDS; B staged per-kt in a 2x8KB LDS
// double buffer (2-phase: stage kt+1 after the barrier, compute kt, one
// barrier per kt -> staging latency overlaps compute). LDS = exactly 80 KB
// -> 2 blocks/CU -> 16 waves/CU = 4 waves/SIMD (2x round-0 occupancy).
// Reduction scratch aliases the dead b0 buffer (kt=7 reads b1; barriers
// order reuse). Accumulator biased by -CLAMP_Y: epilogue is one v_med3 +
// exp2; diagonal contributes e=1 / pv=0, corrected in finalize.
__global__ __launch_bounds__(512, 4) void simloss_tri(
    const unsigned short* __restrict__ fnb, const int* __restrict__ labels,
    float* __restrict__ S, float* __restrict__ P) {
  __shared__ __align__(16) unsigned short Atile[128 * 256];  // 64 KB
  __shared__ __align__(16) unsigned short Bsh[2][128 * 32];  // 16 KB
  // aliases into Bsh[0] (dead during epilogue / after last tile):
  float(*redbuf)[2] = (float(*)[2])(&Bsh[0][0]);             // [128][2] cols
  float(*rslice)[128][2] = (float(*)[128][2])(&Bsh[0][0]);   // [3][128][2] rows

  const int tid = threadIdx.x;
  const int w = tid >> 6;   // wave 0..7
  const int l = tid & 63;
  const int wr = w >> 2;    // wave row group -> 64 rows
  const int wc = w & 3;     // wave col group -> 32 cols
  const int ln15 = l & 15;
  const int q = l >> 4;

  // decode blockIdx.x -> (bi, chunk); row bi has ceil((64-bi)/2) chunks
  int b = blockIdx.x, bi;
  for (bi = 0; bi < 64; ++bi) {
    const int nch = (64 - bi + 1) >> 1;
    if (b < nch) break;
    b -= nch;
  }
  const int ibase = bi * 128;
  const int j0 = bi + b * 2;                      // first j-tile
  const int jn = (64 - j0 < 2) ? (64 - j0) : 2;   // tiles this block (1..2)

  // ---- stage A [128][256] bf16; 16B chunk c of row r stored at c^(r&7)
  {
    const char* gbase = (const char*)fnb;
#pragma unroll
    for (int r = 0; r < 8; ++r) {
      const int off = r * 8192 + w * 1024 + l * 16;
      const int row = off >> 9;                    // 512 B per row
      const int c = ((off >> 4) & 31) ^ (row & 7);
      load16_to_lds(gbase + (size_t)(ibase + row) * 512 + c * 16,
                    (char*)Atile + r * 8192 + w * 1024);
    }
  }

  int rowlab[16];
#pragma unroll
  for (int mi = 0; mi < 4; ++mi)
#pragma unroll
    for (int rg = 0; rg < 4; ++rg)
      rowlab[mi * 4 + rg] = labels[ibase + wr * 64 + mi * 16 + q * 4 + rg];

  float rs[16], rp[16];
#pragma unroll
  for (int t = 0; t < 16; ++t) { rs[t] = 0.f; rp[t] = 0.f; }

  // per-thread B staging geometry: thread loads 16B; row = 64B of k-chunk
  const int boff = w * 1024 + l * 16;       // 0..8191
  const int brow = boff >> 6;               // 0..127
  const int bpos = (l & 3);                 // LDS chunk slot within row
  const int bc = bpos ^ ((brow >> 1) & 3);  // source chunk (swizzle)

  for (int jt = 0; jt < jn; ++jt) {
    const int bj = j0 + jt;
    const int jbase = bj * 128;
    int labJ[2];
#pragma unroll
    for (int ni = 0; ni < 2; ++ni)
      labJ[ni] = labels[jbase + wc * 32 + ni * 16 + ln15];

    f32x4 acc[4][2];
#pragma unroll
    for (int mi = 0; mi < 4; ++mi)
#pragma unroll
      for (int ni = 0; ni < 2; ++ni) acc[mi][ni] = (f32x4)(-CLAMP_Y);

    // cold stage of kt=0 into b0
    load16_to_lds((const char*)fnb + (size_t)(jbase + brow) * 512 + bc * 16,
                  (char*)&Bsh[0][0] + w * 1024);

    // ---- 2-phase K loop: barrier; stage kt+1; compute kt ----
#pragma unroll
    for (int kt = 0; kt < 8; ++kt) {
      __syncthreads();  // drains stage for b[kt&1]; orders b[(kt+1)&1] reuse
      if (kt < 7) {
        load16_to_lds((const char*)fnb + (size_t)(jbase + brow) * 512 +
                          (kt + 1) * 64 + bc * 16,
                      (char*)&Bsh[(kt + 1) & 1][0] + w * 1024);
      }
      const unsigned short* bbuf = &Bsh[kt & 1][0];
      bf16x8 af[4], bfr[2];
#pragma unroll
      for (int mi = 0; mi < 4; ++mi) {
        const int row = wr * 64 + mi * 16 + ln15;
        const int c = (kt * 4 + q) ^ (row & 7);
        af[mi] = *(const bf16x8*)((const char*)Atile + row * 512 + c * 16);
      }
#pragma unroll
      for (int ni = 0; ni < 2; ++ni) {
        const int n = wc * 32 + ni * 16 + ln15;
        const int c = q ^ ((n >> 1) & 3);
        bfr[ni] = *(const bf16x8*)((const char*)bbuf + n * 64 + c * 16);
      }
#pragma unroll
      for (int mi = 0; mi < 4; ++mi)
#pragma unroll
        for (int ni = 0; ni < 2; ++ni)
          acc[mi][ni] = __builtin_amdgcn_mfma_f32_16x16x32_bf16(af[mi], bfr[ni],
                                                                acc[mi][ni], 0, 0, 0);
    }

    // ---- epilogue: exp-sum + positive-sim accumulate (rows + cols) ----
    float cs[2], cp[2];
#pragma unroll
    for (int t = 0; t < 2; ++t) { cs[t] = 0.f; cp[t] = 0.f; }
#pragma unroll
    for (int mi = 0; mi < 4; ++mi)
#pragma unroll
      for (int ni = 0; ni < 2; ++ni)
#pragma unroll
        for (int rg = 0; rg < 4; ++rg) {
          const float yc = clamp_neg(acc[mi][ni][rg]);  // = clamp(sim)*log2e - C
          const float e = fast_exp2(yc);
          const float pv = (labJ[ni] == rowlab[mi * 4 + rg]) ? yc : 0.0f;
          rs[mi * 4 + rg] += e;
          rp[mi * 4 + rg] += pv;
          cs[ni] += e;
          cp[ni] += pv;
        }

    // col sums -> rows of bj via symmetry (skip diagonal tile)
#pragma unroll
    for (int m = 16; m <= 32; m <<= 1)
#pragma unroll
      for (int t = 0; t < 2; ++t) {
        cs[t] += __shfl_xor(cs[t], m, 64);
        cp[t] += __shfl_xor(cp[t], m, 64);
      }
    // wr==1 writes redbuf (aliases b0; kt=7 read b1, top-of-kt7 barrier
    // guarantees everyone is past kt=6's b0 reads)
    if (wr == 1 && q == 0) {
#pragma unroll
      for (int ni = 0; ni < 2; ++ni) {
        const int cl = wc * 32 + ni * 16 + ln15;
        redbuf[cl][0] = cs[ni];
        redbuf[cl][1] = cp[ni];
      }
    }
    __syncthreads();
    if (wr == 0 && q == 0 && bj != bi) {
#pragma unroll
      for (int ni = 0; ni < 2; ++ni) {
        const int cl = wc * 32 + ni * 16 + ln15;
        atomicAdd(&S[jbase + cl], cs[ni] + redbuf[cl][0]);
        atomicAdd(&P[jbase + cl], cp[ni] + redbuf[cl][1]);
      }
    }
    __syncthreads();  // redbuf (b0) reusable: next tile's kt0 stage / row flush
  }

  // ---- row-sum flush: 16-lane reduce, 4-way wc combine in LDS, atomics ----
#pragma unroll
  for (int m = 1; m <= 8; m <<= 1)
#pragma unroll
    for (int t = 0; t < 16; ++t) {
      rs[t] += __shfl_xor(rs[t], m, 64);
      rp[t] += __shfl_xor(rp[t], m, 64);
    }
  if (wc > 0 && ln15 == 0) {
#pragma unroll
    for (int t = 0; t < 16; ++t) {
      const int rl = wr * 64 + (t >> 2) * 16 + q * 4 + (t & 3);
      rslice[wc - 1][rl][0] = rs[t];
      rslice[wc - 1][rl][1] = rp[t];
    }
  }
  __syncthreads();
  if (wc == 0 && ln15 == 0) {
#pragma unroll
    for (int t = 0; t < 16; ++t) {
      const int rl = wr * 64 + (t >> 2) * 16 + q * 4 + (t & 3);
      atomicAdd(&S[ibase + rl],
                rs[t] + rslice[0][rl][0] + rslice[1][rl][0] + rslice[2][rl][0]);
      atomicAdd(&P[ibase + rl],
                rp[t] + rslice[0][rl][1] + rslice[1][rl][1] + rslice[2][rl][1]);
    }
  }
}

// ---------------- finalize: label hist (LDS) + per-row loss + mean ----------
// With biased accumulator: S = sum_j exp(sim_c - 10) incl diag(=1);
// P = sum_{pos} (yc - C) with diag contributing 0  =>
// loss_i = log(S-1) - ln2 * P / cnt      (the +10/-10 cancel exactly)
__global__ __launch_bounds__(1024) void finalize_kernel(
    const float* __restrict__ S, const float* __restrict__ P,
    const int* __restrict__ labels, float* __restrict__ out) {
  __shared__ int h[NCLS];
  if (threadIdx.x < NCLS) h[threadIdx.x] = 0;
  __syncthreads();
  for (int i = threadIdx.x; i < N_ROWS; i += 1024) atomicAdd(&h[labels[i]], 1);
  __syncthreads();

  float lsum = 0.f, vsum = 0.f;
  for (int i = threadIdx.x; i < N_ROWS; i += 1024) {
    const int cnt = h[labels[i]] - 1;  // positives excluding self
    if (cnt > 0) {
      lsum += logf(S[i] - 1.0f) - LN2F * P[i] / (float)cnt;
      vsum += 1.0f;
    }
  }
#pragma unroll
  for (int m = 32; m >= 1; m >>= 1) {
    lsum += __shfl_xor(lsum, m, 64);
    vsum += __shfl_xor(vsum, m, 64);
  }
  __shared__ float ls[16], vs[16];
  const int wv = threadIdx.x >> 6;
  if ((threadIdx.x & 63) == 0) { ls[wv] = lsum; vs[wv] = vsum; }
  __syncthreads();
  if (threadIdx.x == 0) {
    float L = 0.f, V = 0.f;
    for (int k = 0; k < 16; ++k) { L += ls[k]; V += vs[k]; }
    out[0] = (V > 0.f) ? (L / fmaxf(V, 1.0f)) : 0.f;
  }
}

extern "C" void kernel_launch(void* const* d_in, const int* in_sizes, int n_in,
                              void* d_out, int out_size, void* d_ws, size_t ws_size,
                              hipStream_t stream) {
  const float* feat = (const float*)d_in[0];
  const int* labels = (const int*)d_in[1];
  float* out = (float*)d_out;

  char* ws = (char*)d_ws;
  unsigned short* fnb = (unsigned short*)ws;            // bf16 [8192][256], 4 MB
  float* S = (float*)(ws + (size_t)N_ROWS * DIM * 2);   // [8192]
  float* P = S + N_ROWS;                                // [8192]

  normalize_kernel<<<N_ROWS / 4, 256, 0, stream>>>(feat, fnb, S, P);
  simloss_tri<<<1056, 512, 0, stream>>>(fnb, labels, S, P);
  finalize_kernel<<<1, 1024, 0, stream>>>(S, P, labels, out);
}

// Round 3
// 111.476 us; speedup vs baseline: 1.3632x; 1.3632x over previous
//
#include <hip/hip_runtime.h>
#include <hip/hip_bf16.h>
#include <math.h>

#define N_ROWS 8192
#define DIM 256
#define NCLS 128
// scale folded into normalized rows: sqrt((1/0.07) * log2(e))
#define ROW_SCALE 4.539816f
#define CLAMP_Y 14.426950408889634f   // 10 * log2(e)
#define NEG2C (-28.853900817779268f)  // -2 * CLAMP_Y
#define LN2F 0.6931471805599453f

typedef short bf16x8 __attribute__((ext_vector_type(8)));
typedef float f32x4 __attribute__((ext_vector_type(4)));

#define AS1 __attribute__((address_space(1)))
#define AS3 __attribute__((address_space(3)))

__device__ __forceinline__ void load16_to_lds(const void* g, void* lds) {
  // LDS dest = wave-uniform base + lane*16 (HW rule); gptr is per-lane
  __builtin_amdgcn_global_load_lds((const AS1 void*)g, (AS3 void*)lds, 16, 0, 0);
}

__device__ __forceinline__ unsigned short f2bf(float x) {
  union { __hip_bfloat16 b; unsigned short u; } cv;
  cv.b = __float2bfloat16(x);
  return cv.u;
}

__device__ __forceinline__ float fast_exp2(float x) {
#if __has_builtin(__builtin_amdgcn_exp2f)
  return __builtin_amdgcn_exp2f(x);
#else
  return exp2f(x);
#endif
}

// clamp(x, -2C, 0) in one v_med3_f32
__device__ __forceinline__ float clamp_neg(float x) {
#if __has_builtin(__builtin_amdgcn_fmed3f)
  return __builtin_amdgcn_fmed3f(x, NEG2C, 0.0f);
#else
  return fminf(0.0f, fmaxf(NEG2C, x));
#endif
}

// ---------------- row-normalize*ROW_SCALE -> bf16, zero S/P -----------------
__global__ __launch_bounds__(256) void normalize_kernel(const float* __restrict__ f,
                                                        unsigned short* __restrict__ fnb,
                                                        float* __restrict__ S,
                                                        float* __restrict__ P) {
  const int row = blockIdx.x * 4 + (threadIdx.x >> 6);
  const int l = threadIdx.x & 63;
  const float4 v = ((const float4*)(f + (size_t)row * DIM))[l];
  float ss = v.x * v.x + v.y * v.y + v.z * v.z + v.w * v.w;
#pragma unroll
  for (int m = 32; m >= 1; m >>= 1) ss += __shfl_xor(ss, m, 64);
  const float inv = ROW_SCALE / fmaxf(sqrtf(ss), 1e-6f);
  ushort4 o;
  o.x = f2bf(v.x * inv);
  o.y = f2bf(v.y * inv);
  o.z = f2bf(v.z * inv);
  o.w = f2bf(v.w * inv);
  ((ushort4*)(fnb + (size_t)row * DIM))[l] = o;
  if (l == 0) { S[row] = 0.f; P[row] = 0.f; }
}

// ---------------- triangular-strip GEMM + exp/positive reductions -----------
// 1056 blocks x 256 threads (4 waves): block = (bi, chunk of up to 2 j-tiles).
// A (128x256 bf16, 64 KB) resident in LDS; B staged per-kt into a 2x8KB LDS
// double buffer, 2-phase: stage kt+1 FIRST, then compute kt, then ONE barrier
// per kt (the implicit vmcnt(0) drain lands a full compute phase after the
// load issue). LDS = exactly 80 KB -> 2 blocks/CU. launch_bounds(256,2)
// keeps the register regime of the proven round-0 kernel (no spills).
// Reduction scratch aliases the dead Bsh[0]. Accumulator biased by -CLAMP_Y:
// epilogue is one v_med3 + exp2; diagonal contributes e=1 / pv=0 exactly.
__global__ __launch_bounds__(256, 2) void simloss_tri(
    const unsigned short* __restrict__ fnb, const int* __restrict__ labels,
    float* __restrict__ S, float* __restrict__ P) {
  __shared__ __align__(16) unsigned short Atile[128 * 256];  // 64 KB
  __shared__ __align__(16) unsigned short Bsh[2][128 * 32];  // 16 KB
  // alias into Bsh[0] (dead during epilogue / after last tile):
  float(*redbuf)[2] = (float(*)[2])(&Bsh[0][0]);             // [128][2]

  const int tid = threadIdx.x;
  const int w = tid >> 6;   // wave 0..3
  const int l = tid & 63;
  const int wr = w >> 1;    // wave row -> 64 rows
  const int wc = w & 1;     // wave col -> 64 cols
  const int ln15 = l & 15;
  const int q = l >> 4;

  // decode blockIdx.x -> (bi, chunk); row bi has ceil((64-bi)/2) chunks
  int b = blockIdx.x, bi;
  for (bi = 0; bi < 64; ++bi) {
    const int nch = (64 - bi + 1) >> 1;
    if (b < nch) break;
    b -= nch;
  }
  const int ibase = bi * 128;
  const int j0 = bi + b * 2;                      // first j-tile
  const int jn = (64 - j0 < 2) ? (64 - j0) : 2;   // tiles this block (1..2)

  // ---- stage A [128][256] bf16; 16B chunk c of row r stored at c^(r&7)
  {
    const char* gbase = (const char*)fnb;
#pragma unroll
    for (int r = 0; r < 16; ++r) {
      const int off = r * 4096 + w * 1024 + l * 16;
      const int row = off >> 9;                    // 512 B per row
      const int c = ((off >> 4) & 31) ^ (row & 7);
      load16_to_lds(gbase + (size_t)(ibase + row) * 512 + c * 16,
                    (char*)Atile + r * 4096 + w * 1024);
    }
  }

  int rowlab[16];
#pragma unroll
  for (int mi = 0; mi < 4; ++mi)
#pragma unroll
    for (int rg = 0; rg < 4; ++rg)
      rowlab[mi * 4 + rg] = labels[ibase + wr * 64 + mi * 16 + q * 4 + rg];

  float rs[16], rp[16];
#pragma unroll
  for (int t = 0; t < 16; ++t) { rs[t] = 0.f; rp[t] = 0.f; }

  for (int jt = 0; jt < jn; ++jt) {
    const int bj = j0 + jt;
    const int jbase = bj * 128;

    // cold stage kt=0 -> Bsh[0] (prev tile's epilogue barrier ordered reuse)
#pragma unroll
    for (int r = 0; r < 2; ++r) {
      const int off = r * 1024 + l * 16;
      const int row = w * 32 + (off >> 6);         // 64 B per row
      const int c = ((off >> 4) & 3) ^ ((row >> 1) & 3);
      load16_to_lds((const char*)fnb + (size_t)(jbase + row) * 512 + c * 16,
                    (char*)&Bsh[0][0] + w * 2048 + r * 1024);
    }

    int labJ[4];
#pragma unroll
    for (int ni = 0; ni < 4; ++ni)
      labJ[ni] = labels[jbase + wc * 64 + ni * 16 + ln15];

    f32x4 acc[4][4];
#pragma unroll
    for (int mi = 0; mi < 4; ++mi)
#pragma unroll
      for (int ni = 0; ni < 4; ++ni) acc[mi][ni] = (f32x4)(-CLAMP_Y);

    __syncthreads();  // drain A (first tile) + cold B stage

    // ---- 2-phase K loop: stage kt+1; compute kt; one barrier per kt ----
#pragma unroll
    for (int kt = 0; kt < 8; ++kt) {
      if (kt < 7) {
        // stage kt+1 into the other buffer (its last reads were kt-1,
        // ordered by the end-of-(kt-1) barrier)
#pragma unroll
        for (int r = 0; r < 2; ++r) {
          const int off = r * 1024 + l * 16;
          const int row = w * 32 + (off >> 6);
          const int c = ((off >> 4) & 3) ^ ((row >> 1) & 3);
          load16_to_lds((const char*)fnb + (size_t)(jbase + row) * 512 +
                            (kt + 1) * 64 + c * 16,
                        (char*)&Bsh[(kt + 1) & 1][0] + w * 2048 + r * 1024);
        }
      }
      const unsigned short* bbuf = &Bsh[kt & 1][0];
      bf16x8 af[4], bfr[4];
#pragma unroll
      for (int mi = 0; mi < 4; ++mi) {
        const int row = wr * 64 + mi * 16 + ln15;
        const int c = (kt * 4 + q) ^ (row & 7);
        af[mi] = *(const bf16x8*)((const char*)Atile + row * 512 + c * 16);
      }
#pragma unroll
      for (int ni = 0; ni < 4; ++ni) {
        const int n = wc * 64 + ni * 16 + ln15;
        const int c = q ^ ((n >> 1) & 3);
        bfr[ni] = *(const bf16x8*)((const char*)bbuf + n * 64 + c * 16);
      }
#pragma unroll
      for (int mi = 0; mi < 4; ++mi)
#pragma unroll
        for (int ni = 0; ni < 4; ++ni)
          acc[mi][ni] = __builtin_amdgcn_mfma_f32_16x16x32_bf16(af[mi], bfr[ni],
                                                                acc[mi][ni], 0, 0, 0);
      if (kt < 7) __syncthreads();  // drains stage of kt+1; orders buffer reuse
    }

    // ---- epilogue: exp-sum + positive-sim accumulate (rows + cols) ----
    float cs[4], cp[4];
#pragma unroll
    for (int t = 0; t < 4; ++t) { cs[t] = 0.f; cp[t] = 0.f; }
#pragma unroll
    for (int mi = 0; mi < 4; ++mi)
#pragma unroll
      for (int ni = 0; ni < 4; ++ni)
#pragma unroll
        for (int rg = 0; rg < 4; ++rg) {
          const float yc = clamp_neg(acc[mi][ni][rg]);  // clamp(sim)*log2e - C
          const float e = fast_exp2(yc);
          const float pv = (labJ[ni] == rowlab[mi * 4 + rg]) ? yc : 0.0f;
          rs[mi * 4 + rg] += e;
          rp[mi * 4 + rg] += pv;
          cs[ni] += e;
          cp[ni] += pv;
        }

    // col sums -> rows of bj via symmetry (skip diagonal tile)
#pragma unroll
    for (int m = 16; m <= 32; m <<= 1)
#pragma unroll
      for (int t = 0; t < 4; ++t) {
        cs[t] += __shfl_xor(cs[t], m, 64);
        cp[t] += __shfl_xor(cp[t], m, 64);
      }
    // redbuf aliases Bsh[0]: last b0 reads were kt=6, ordered by its barrier;
    // kt=7 reads only b1.
    if (wr == 1 && q == 0) {
#pragma unroll
      for (int ni = 0; ni < 4; ++ni) {
        const int cl = wc * 64 + ni * 16 + ln15;
        redbuf[cl][0] = cs[ni];
        redbuf[cl][1] = cp[ni];
      }
    }
    __syncthreads();
    if (wr == 0 && q == 0 && bj != bi) {
#pragma unroll
      for (int ni = 0; ni < 4; ++ni) {
        const int cl = wc * 64 + ni * 16 + ln15;
        atomicAdd(&S[jbase + cl], cs[ni] + redbuf[cl][0]);
        atomicAdd(&P[jbase + cl], cp[ni] + redbuf[cl][1]);
      }
    }
    __syncthreads();  // redbuf reads done before next tile's cold stage / flush
  }

  // ---- row-sum flush: 16-lane reduce, wc-pair combine in LDS, atomics ----
#pragma unroll
  for (int m = 1; m <= 8; m <<= 1)
#pragma unroll
    for (int t = 0; t < 16; ++t) {
      rs[t] += __shfl_xor(rs[t], m, 64);
      rp[t] += __shfl_xor(rp[t], m, 64);
    }
  if (wc == 1 && ln15 == 0) {
#pragma unroll
    for (int t = 0; t < 16; ++t) {
      const int rl = wr * 64 + (t >> 2) * 16 + q * 4 + (t & 3);
      redbuf[rl][0] = rs[t];
      redbuf[rl][1] = rp[t];
    }
  }
  __syncthreads();
  if (wc == 0 && ln15 == 0) {
#pragma unroll
    for (int t = 0; t < 16; ++t) {
      const int rl = wr * 64 + (t >> 2) * 16 + q * 4 + (t & 3);
      atomicAdd(&S[ibase + rl], rs[t] + redbuf[rl][0]);
      atomicAdd(&P[ibase + rl], rp[t] + redbuf[rl][1]);
    }
  }
}

// ---------------- finalize: label hist (LDS) + per-row loss + mean ----------
// With biased accumulator: S = sum_j exp(sim_c - 10) incl diag(=1);
// P = sum_{pos} (sim_c*log2e - C) with diag contributing 0  =>
// loss_i = log(S-1) - ln2 * P / cnt      (the +10/-10 cancel exactly)
__global__ __launch_bounds__(1024) void finalize_kernel(
    const float* __restrict__ S, const float* __restrict__ P,
    const int* __restrict__ labels, float* __restrict__ out) {
  __shared__ int h[NCLS];
  if (threadIdx.x < NCLS) h[threadIdx.x] = 0;
  __syncthreads();
  for (int i = threadIdx.x; i < N_ROWS; i += 1024) atomicAdd(&h[labels[i]], 1);
  __syncthreads();

  float lsum = 0.f, vsum = 0.f;
  for (int i = threadIdx.x; i < N_ROWS; i += 1024) {
    const int cnt = h[labels[i]] - 1;  // positives excluding self
    if (cnt > 0) {
      lsum += logf(S[i] - 1.0f) - LN2F * P[i] / (float)cnt;
      vsum += 1.0f;
    }
  }
#pragma unroll
  for (int m = 32; m >= 1; m >>= 1) {
    lsum += __shfl_xor(lsum, m, 64);
    vsum += __shfl_xor(vsum, m, 64);
  }
  __shared__ float ls[16], vs[16];
  const int wv = threadIdx.x >> 6;
  if ((threadIdx.x & 63) == 0) { ls[wv] = lsum; vs[wv] = vsum; }
  __syncthreads();
  if (threadIdx.x == 0) {
    float L = 0.f, V = 0.f;
    for (int k = 0; k < 16; ++k) { L += ls[k]; V += vs[k]; }
    out[0] = (V > 0.f) ? (L / fmaxf(V, 1.0f)) : 0.f;
  }
}

extern "C" void kernel_launch(void* const* d_in, const int* in_sizes, int n_in,
                              void* d_out, int out_size, void* d_ws, size_t ws_size,
                              hipStream_t stream) {
  const float* feat = (const float*)d_in[0];
  const int* labels = (const int*)d_in[1];
  float* out = (float*)d_out;

  char* ws = (char*)d_ws;
  unsigned short* fnb = (unsigned short*)ws;            // bf16 [8192][256], 4 MB
  float* S = (float*)(ws + (size_t)N_ROWS * DIM * 2);   // [8192]
  float* P = S + N_ROWS;                                // [8192]

  normalize_kernel<<<N_ROWS / 4, 256, 0, stream>>>(feat, fnb, S, P);
  simloss_tri<<<1056, 256, 0, stream>>>(fnb, labels, S, P);
  finalize_kernel<<<1, 1024, 0, stream>>>(S, P, labels, out);
}